// Round 2
// baseline (618.714 us; speedup 1.0000x reference)
//
#include <hip/hip_runtime.h>
#include <math.h>

// SE3Transformer fused kernel, fp32, 2 nodes (16 edges) per 256-thread block.
#define NN    20000
#define KEDGE 8
#define NBF   16
#define HID   64
#define A0c   16
#define A1c   8
#define Q0c   8
#define Q1c   4
#define B0c   16
#define B1c   8
#define WKC   288   // A0*Q0 + A1*Q0 + A0*Q1 + A1*Q1
#define WVC   576   // A0*B0 + A1*B0 + A0*B1 + A1*B1
#define TOTC  864
#define EPB   16    // edges per block
#define NPB   2     // nodes per block
#define WPAD  872   // padded wkv row

__global__ __launch_bounds__(256, 2)
void se3_fused(const float* __restrict__ f,
               const float* __restrict__ pos,
               const float* __restrict__ W1k,
               const float* __restrict__ W2k,
               const float* __restrict__ W1v,
               const float* __restrict__ W2v,
               const float* __restrict__ Wq0,
               const float* __restrict__ Wq1,
               const float* __restrict__ Wd0,
               const float* __restrict__ Wd1,
               const int* __restrict__ esrc,
               float* __restrict__ out)
{
    const int tid   = threadIdx.x;
    const int e0    = blockIdx.x * EPB;
    const int node0 = blockIdx.x * NPB;

    __shared__ float s_fs0[EPB][A0c];
    __shared__ float s_fs1[EPB][A1c*3];
    __shared__ float s_dot[EPB][A1c];
    __shared__ float s_y1[EPB][4];
    __shared__ float s_basis[EPB][NBF];
    __shared__ float s_cut[EPB];
    __shared__ int   s_src[EPB];
    __shared__ float s_r[EPB];
    __shared__ __align__(16) float s_hk[HID][EPB];
    __shared__ __align__(16) float s_hv[HID][EPB];
    __shared__ float s_wkv[EPB][WPAD];
    __shared__ float s_kv[EPB][60];
    __shared__ float s_q0[NPB][Q0c];
    __shared__ float s_q1[NPB][Q1c*3];
    __shared__ float s_logit[EPB];
    __shared__ float s_we[EPB];

    // ---- Phase A1: per-edge geometry ----
    if (tid < EPB) {
        int e = tid;
        int src = esrc[e0 + e];
        int dst = node0 + (e >> 3);   // edge_dst = repeat(arange(N), K), structural
        s_src[e] = src;
        float dx = pos[src*3+0] - pos[dst*3+0];
        float dy = pos[src*3+1] - pos[dst*3+1];
        float dz = pos[src*3+2] - pos[dst*3+2];
        float r  = sqrtf(dx*dx + dy*dy + dz*dz + 1e-12f);
        s_r[e] = r;
        const float s3 = 1.7320508075688772f;
        float inv_r = 1.0f / r;
        s_y1[e][0] = s3*dx*inv_r;
        s_y1[e][1] = s3*dy*inv_r;
        s_y1[e][2] = s3*dz*inv_r;
        float xcut = 10.0f*(1.0f - r*(1.0f/3.5f));
        s_cut[e] = (xcut > 0.0f) ? expf(-1.0f/xcut) : 0.0f;
    }
    __syncthreads();

    // ---- Phase A2: basis, gather src features, queries ----
    {
        int e = tid >> 4, c = tid & 15;
        float r = s_r[e];
        const float step = 3.5f / 17.0f;
        float ctr = step * (float)(c + 1);
        float tt  = (r - ctr) * (1.0f/step);
        s_basis[e][c] = expf(-tt*tt) * (4.0f/1.12f);
        s_fs0[e][c]   = f[s_src[e]*40 + c];
    }
    for (int rep = 0; rep < 2; rep++) {
        int slot = rep*256 + tid;
        if (slot < EPB*24) {
            int e = slot/24, c = slot%24;
            s_fs1[e][c] = f[s_src[e]*40 + 16 + c];
        }
    }
    if (tid < NPB*Q0c) {                       // q0 = f0 @ Wq0 / 4
        int n = tid >> 3, q = tid & 7;
        const float* fn = f + (node0+n)*40;
        float acc = 0.f;
        #pragma unroll
        for (int a = 0; a < A0c; a++) acc += fn[a]*Wq0[a*Q0c+q];
        s_q0[n][q] = acc * 0.25f;
    }
    if (tid >= 64 && tid < 64 + NPB*Q1c*3) {   // q1 = einsum(f1,Wq1)/sqrt(8)
        int s = tid - 64;
        int n = s/12, qi = s%12, q = qi/3, i = qi%3;
        const float* fn = f + (node0+n)*40 + 16;
        float acc = 0.f;
        #pragma unroll
        for (int a = 0; a < A1c; a++) acc += fn[a*3+i]*Wq1[a*Q1c+q];
        s_q1[n][qi] = acc * 0.35355339059327373f;
    }
    __syncthreads();

    // ---- Phase B: dot11 + hidden vectors hk/hv ----
    if (tid < EPB*A1c) {
        int e = tid >> 3, a = tid & 7;
        float acc = s_fs1[e][a*3+0]*s_y1[e][0]
                  + s_fs1[e][a*3+1]*s_y1[e][1]
                  + s_fs1[e][a*3+2]*s_y1[e][2];
        s_dot[e][a] = acc * 0.5773502691896258f;   // /sqrt(3)
    }
    {
        int wid = tid >> 6, lane = tid & 63;
        for (int rep = 0; rep < 4; rep++) {
            int e = rep*4 + wid;
            float ak = 0.f, av = 0.f;
            #pragma unroll
            for (int nb = 0; nb < NBF; nb++) {
                float b = s_basis[e][nb];
                ak += b * W1k[nb*HID + lane];
                av += b * W1v[nb*HID + lane];
            }
            ak *= 0.25f; av *= 0.25f;              // W1/sqrt(16)
            ak = ak / (1.0f + expf(-ak));          // silu
            av = av / (1.0f + expf(-av));
            s_hk[lane][e] = ak;
            s_hv[lane][e] = av;
        }
    }
    __syncthreads();

    // ---- Phase C: wkv[e][j] = (h[e] @ W2)[j] / 8, 16 edges per thread-column ----
    for (int t = 0; t < 4; t++) {
        int j = tid + 256*t;
        if (j < TOTC) {
            const float* wp;
            const float* hh;
            int stride;
            if (j < WKC) { wp = W2k + j;         hh = &s_hk[0][0]; stride = WKC; }
            else         { wp = W2v + (j - WKC); hh = &s_hv[0][0]; stride = WVC; }
            float acc[EPB];
            #pragma unroll
            for (int e = 0; e < EPB; e++) acc[e] = 0.f;
            #pragma unroll 4
            for (int h = 0; h < HID; h++) {
                float w = wp[h*stride];
                #pragma unroll
                for (int eq = 0; eq < 4; eq++) {
                    float4 h4 = *(const float4*)(hh + h*EPB + eq*4);
                    acc[eq*4+0] += h4.x*w;
                    acc[eq*4+1] += h4.y*w;
                    acc[eq*4+2] += h4.z*w;
                    acc[eq*4+3] += h4.w*w;
                }
            }
            #pragma unroll
            for (int e = 0; e < EPB; e++) s_wkv[e][j] = acc[e]*0.125f;  // W2/sqrt(64)
        }
    }
    __syncthreads();

    // ---- Phase D: tensor product -> k0,k1,v0,v1 (60 outputs/edge) ----
    const float nrm = 0.2041241452319315f;   // 1/sqrt(A0+A1)
    for (int rep = 0; rep < 4; rep++) {
        int slot = rep*256 + tid;
        if (slot < EPB*60) {
            int e = slot/60, o = slot%60;
            const float* wr = &s_wkv[e][0];
            float val = 0.f;
            if (o < 8) {                       // k0[b]
                int b = o;
                #pragma unroll
                for (int a = 0; a < A0c; a++) val += s_fs0[e][a]*wr[a*8+b];
                #pragma unroll
                for (int a = 0; a < A1c; a++) val += s_dot[e][a]*wr[128+a*8+b];
            } else if (o < 20) {               // k1[b][i]
                int idx = o-8; int b = idx/3, i = idx%3;
                float t0 = 0.f, t1 = 0.f;
                #pragma unroll
                for (int a = 0; a < A0c; a++) t0 += s_fs0[e][a]*wr[192+a*4+b];
                #pragma unroll
                for (int a = 0; a < A1c; a++) t1 += s_fs1[e][a*3+i]*wr[256+a*4+b];
                val = t0*s_y1[e][i] + t1;
            } else if (o < 36) {               // v0[b]
                int b = o-20;
                #pragma unroll
                for (int a = 0; a < A0c; a++) val += s_fs0[e][a]*wr[288+a*16+b];
                #pragma unroll
                for (int a = 0; a < A1c; a++) val += s_dot[e][a]*wr[288+256+a*16+b];
            } else {                           // v1[b][i]
                int idx = o-36; int b = idx/3, i = idx%3;
                float t0 = 0.f, t1 = 0.f;
                #pragma unroll
                for (int a = 0; a < A0c; a++) t0 += s_fs0[e][a]*wr[288+384+a*8+b];
                #pragma unroll
                for (int a = 0; a < A1c; a++) t1 += s_fs1[e][a*3+i]*wr[288+512+a*8+b];
                val = t0*s_y1[e][i] + t1;
            }
            s_kv[e][o] = val * nrm;
        }
    }
    __syncthreads();

    // ---- Phase E: logits ----
    if (tid < EPB) {
        int e = tid, n = e >> 3;
        float s0 = 0.f;
        #pragma unroll
        for (int a = 0; a < Q0c; a++) {
            float qa = s_q0[n][a];
            #pragma unroll
            for (int b = 0; b < Q0c; b++) s0 += qa * s_kv[e][b] * Wd0[a*8+b];
        }
        float s1 = 0.f;
        #pragma unroll
        for (int a = 0; a < Q1c; a++) {
            #pragma unroll
            for (int b = 0; b < Q1c; b++) {
                float d = s_q1[n][a*3+0]*s_kv[e][8+b*3+0]
                        + s_q1[n][a*3+1]*s_kv[e][8+b*3+1]
                        + s_q1[n][a*3+2]*s_kv[e][8+b*3+2];
                s1 += d * Wd1[a*4+b];
            }
        }
        s_logit[e] = (s0 + s1*0.5773502691896258f) * 0.11180339887498948f; // dnorm=1/sqrt(80)
    }
    __syncthreads();

    // ---- Phase F: per-node softmax over 8 edges ----
    if (tid < NPB) {
        int n = tid;
        float m = -1e30f;
        #pragma unroll
        for (int e = 0; e < 8; e++) m = fmaxf(m, s_logit[n*8+e]);
        float z[8]; float s = 0.f;
        #pragma unroll
        for (int e = 0; e < 8; e++) { z[e] = expf(s_logit[n*8+e]-m); s += z[e]; }
        float inv_s = 1.0f / s;
        #pragma unroll
        for (int e = 0; e < 8; e++) {
            float alpha = z[e]*inv_s * s_cut[n*8+e];
            s_we[n*8+e] = sqrtf(alpha + 1e-12f);
        }
    }
    __syncthreads();

    // ---- Phase G: weighted sum -> out ----
    if (tid < NPB*40) {
        int n = tid/40, c = tid%40;
        float acc = 0.f;
        #pragma unroll
        for (int e = 0; e < 8; e++) acc += s_we[n*8+e]*s_kv[n*8+e][20+c];
        out[(node0+n)*40 + c] = acc;
    }
}

extern "C" void kernel_launch(void* const* d_in, const int* in_sizes, int n_in,
                              void* d_out, int out_size, void* d_ws, size_t ws_size,
                              hipStream_t stream) {
    const float* f    = (const float*)d_in[0];
    const float* pos  = (const float*)d_in[1];
    const float* W1k  = (const float*)d_in[2];
    const float* W2k  = (const float*)d_in[3];
    const float* W1v  = (const float*)d_in[4];
    const float* W2v  = (const float*)d_in[5];
    const float* Wq0  = (const float*)d_in[6];
    const float* Wq1  = (const float*)d_in[7];
    const float* Wd0  = (const float*)d_in[8];
    const float* Wd1  = (const float*)d_in[9];
    // d_in[10] = batch (unused by reference math)
    const int*   esrc = (const int*)d_in[11];
    float* out = (float*)d_out;

    dim3 grid(NN / NPB);
    dim3 block(256);
    hipLaunchKernelGGL(se3_fused, grid, block, 0, stream,
                       f, pos, W1k, W2k, W1v, W2v, Wq0, Wq1, Wd0, Wd1, esrc, out);
}

// Round 8
// 507.278 us; speedup vs baseline: 1.2197x; 1.2197x over previous
//
#include <hip/hip_runtime.h>
#include <math.h>

// SE3Transformer fused kernel, fp32, 2 nodes (16 edges) per 256-thread block.
// R3: Phase C register-blocked 8 edges x 8 cols per thread (LDS-issue fix).
#define NN    20000
#define KEDGE 8
#define NBF   16
#define HID   64
#define A0c   16
#define A1c   8
#define Q0c   8
#define Q1c   4
#define B0c   16
#define B1c   8
#define WKC   288   // A0*Q0 + A1*Q0 + A0*Q1 + A1*Q1
#define WVC   576   // A0*B0 + A1*B0 + A0*B1 + A1*B1
#define TOTC  864
#define EPB   16    // edges per block
#define NPB   2     // nodes per block
#define WPAD  872   // padded wkv row

__global__ __launch_bounds__(256, 2)
void se3_fused(const float* __restrict__ f,
               const float* __restrict__ pos,
               const float* __restrict__ W1k,
               const float* __restrict__ W2k,
               const float* __restrict__ W1v,
               const float* __restrict__ W2v,
               const float* __restrict__ Wq0,
               const float* __restrict__ Wq1,
               const float* __restrict__ Wd0,
               const float* __restrict__ Wd1,
               const int* __restrict__ esrc,
               float* __restrict__ out)
{
    const int tid   = threadIdx.x;
    const int e0    = blockIdx.x * EPB;
    const int node0 = blockIdx.x * NPB;

    __shared__ float s_fs0[EPB][A0c];
    __shared__ float s_fs1[EPB][A1c*3];
    __shared__ float s_dot[EPB][A1c];
    __shared__ float s_y1[EPB][4];
    __shared__ float s_basis[EPB][NBF];
    __shared__ float s_cut[EPB];
    __shared__ int   s_src[EPB];
    __shared__ float s_r[EPB];
    __shared__ __align__(16) float s_hk[HID][EPB];
    __shared__ __align__(16) float s_hv[HID][EPB];
    __shared__ float s_wkv[EPB][WPAD];
    __shared__ float s_kv[EPB][60];
    __shared__ float s_q0[NPB][Q0c];
    __shared__ float s_q1[NPB][Q1c*3];
    __shared__ float s_logit[EPB];
    __shared__ float s_we[EPB];

    // ---- Phase A1: per-edge geometry ----
    if (tid < EPB) {
        int e = tid;
        int src = esrc[e0 + e];
        int dst = node0 + (e >> 3);   // edge_dst = repeat(arange(N), K), structural
        s_src[e] = src;
        float dx = pos[src*3+0] - pos[dst*3+0];
        float dy = pos[src*3+1] - pos[dst*3+1];
        float dz = pos[src*3+2] - pos[dst*3+2];
        float r  = sqrtf(dx*dx + dy*dy + dz*dz + 1e-12f);
        s_r[e] = r;
        const float s3 = 1.7320508075688772f;
        float inv_r = 1.0f / r;
        s_y1[e][0] = s3*dx*inv_r;
        s_y1[e][1] = s3*dy*inv_r;
        s_y1[e][2] = s3*dz*inv_r;
        float xcut = 10.0f*(1.0f - r*(1.0f/3.5f));
        s_cut[e] = (xcut > 0.0f) ? expf(-1.0f/xcut) : 0.0f;
    }
    __syncthreads();

    // ---- Phase A2: basis, gather src features, queries ----
    {
        int e = tid >> 4, c = tid & 15;
        float r = s_r[e];
        const float step = 3.5f / 17.0f;
        float ctr = step * (float)(c + 1);
        float tt  = (r - ctr) * (1.0f/step);
        s_basis[e][c] = expf(-tt*tt) * (4.0f/1.12f);
        s_fs0[e][c]   = f[s_src[e]*40 + c];
    }
    for (int rep = 0; rep < 2; rep++) {
        int slot = rep*256 + tid;
        if (slot < EPB*24) {
            int e = slot/24, c = slot%24;
            s_fs1[e][c] = f[s_src[e]*40 + 16 + c];
        }
    }
    if (tid < NPB*Q0c) {                       // q0 = f0 @ Wq0 / 4
        int n = tid >> 3, q = tid & 7;
        const float* fn = f + (node0+n)*40;
        float acc = 0.f;
        #pragma unroll
        for (int a = 0; a < A0c; a++) acc += fn[a]*Wq0[a*Q0c+q];
        s_q0[n][q] = acc * 0.25f;
    }
    if (tid >= 64 && tid < 64 + NPB*Q1c*3) {   // q1 = einsum(f1,Wq1)/sqrt(8)
        int s = tid - 64;
        int n = s/12, qi = s%12, q = qi/3, i = qi%3;
        const float* fn = f + (node0+n)*40 + 16;
        float acc = 0.f;
        #pragma unroll
        for (int a = 0; a < A1c; a++) acc += fn[a*3+i]*Wq1[a*Q1c+q];
        s_q1[n][qi] = acc * 0.35355339059327373f;
    }
    __syncthreads();

    // ---- Phase B: dot11 + hidden vectors hk/hv ----
    if (tid < EPB*A1c) {
        int e = tid >> 3, a = tid & 7;
        float acc = s_fs1[e][a*3+0]*s_y1[e][0]
                  + s_fs1[e][a*3+1]*s_y1[e][1]
                  + s_fs1[e][a*3+2]*s_y1[e][2];
        s_dot[e][a] = acc * 0.5773502691896258f;   // /sqrt(3)
    }
    {
        int wid = tid >> 6, lane = tid & 63;
        for (int rep = 0; rep < 4; rep++) {
            int e = rep*4 + wid;
            float ak = 0.f, av = 0.f;
            #pragma unroll
            for (int nb = 0; nb < NBF; nb++) {
                float b = s_basis[e][nb];
                ak += b * W1k[nb*HID + lane];
                av += b * W1v[nb*HID + lane];
            }
            ak *= 0.25f; av *= 0.25f;              // W1/sqrt(16)
            ak = ak / (1.0f + expf(-ak));          // silu
            av = av / (1.0f + expf(-av));
            s_hk[lane][e] = ak;
            s_hv[lane][e] = av;
        }
    }
    __syncthreads();

    // ---- Phase C: wkv = (h @ W2)/8 as 8x8 register-blocked GEMM ----
    // thread -> (eg = tid&1 : edges eg*8..eg*8+7, jg = tid>>1 : cols jg*8..jg*8+7)
    {
        int eg = tid & 1;
        int jg = tid >> 1;
        if (jg < TOTC/8) {
            int j = jg * 8;
            const float* wp;
            const float* hh;
            int stride;
            if (j < WKC) { wp = W2k + j;         hh = &s_hk[0][0] + eg*8; stride = WKC; }
            else         { wp = W2v + (j - WKC); hh = &s_hv[0][0] + eg*8; stride = WVC; }
            float acc[8][8];
            #pragma unroll
            for (int e = 0; e < 8; e++)
                #pragma unroll
                for (int c = 0; c < 8; c++) acc[e][c] = 0.f;
            #pragma unroll 2
            for (int h = 0; h < HID; h++) {
                float4 ha = *(const float4*)(hh + h*EPB);
                float4 hb = *(const float4*)(hh + h*EPB + 4);
                float4 w0 = *(const float4*)(wp + h*stride);
                float4 w1 = *(const float4*)(wp + h*stride + 4);
                float hv[8] = {ha.x, ha.y, ha.z, ha.w, hb.x, hb.y, hb.z, hb.w};
                float wv[8] = {w0.x, w0.y, w0.z, w0.w, w1.x, w1.y, w1.z, w1.w};
                #pragma unroll
                for (int e = 0; e < 8; e++)
                    #pragma unroll
                    for (int c = 0; c < 8; c++)
                        acc[e][c] += hv[e] * wv[c];
            }
            #pragma unroll
            for (int e = 0; e < 8; e++)
                #pragma unroll
                for (int c = 0; c < 8; c++)
                    s_wkv[eg*8 + e][j + c] = acc[e][c] * 0.125f;   // W2/sqrt(64)
        }
    }
    __syncthreads();

    // ---- Phase D: tensor product -> k0,k1,v0,v1 (60 outputs/edge) ----
    const float nrm = 0.2041241452319315f;   // 1/sqrt(A0+A1)
    for (int rep = 0; rep < 4; rep++) {
        int slot = rep*256 + tid;
        if (slot < EPB*60) {
            int e = slot/60, o = slot%60;
            const float* wr = &s_wkv[e][0];
            float val = 0.f;
            if (o < 8) {                       // k0[b]
                int b = o;
                #pragma unroll
                for (int a = 0; a < A0c; a++) val += s_fs0[e][a]*wr[a*8+b];
                #pragma unroll
                for (int a = 0; a < A1c; a++) val += s_dot[e][a]*wr[128+a*8+b];
            } else if (o < 20) {               // k1[b][i]
                int idx = o-8; int b = idx/3, i = idx%3;
                float t0 = 0.f, t1 = 0.f;
                #pragma unroll
                for (int a = 0; a < A0c; a++) t0 += s_fs0[e][a]*wr[192+a*4+b];
                #pragma unroll
                for (int a = 0; a < A1c; a++) t1 += s_fs1[e][a*3+i]*wr[256+a*4+b];
                val = t0*s_y1[e][i] + t1;
            } else if (o < 36) {               // v0[b]
                int b = o-20;
                #pragma unroll
                for (int a = 0; a < A0c; a++) val += s_fs0[e][a]*wr[288+a*16+b];
                #pragma unroll
                for (int a = 0; a < A1c; a++) val += s_dot[e][a]*wr[288+256+a*16+b];
            } else {                           // v1[b][i]
                int idx = o-36; int b = idx/3, i = idx%3;
                float t0 = 0.f, t1 = 0.f;
                #pragma unroll
                for (int a = 0; a < A0c; a++) t0 += s_fs0[e][a]*wr[288+384+a*8+b];
                #pragma unroll
                for (int a = 0; a < A1c; a++) t1 += s_fs1[e][a*3+i]*wr[288+512+a*8+b];
                val = t0*s_y1[e][i] + t1;
            }
            s_kv[e][o] = val * nrm;
        }
    }
    __syncthreads();

    // ---- Phase E: logits ----
    if (tid < EPB) {
        int e = tid, n = e >> 3;
        float s0 = 0.f;
        #pragma unroll
        for (int a = 0; a < Q0c; a++) {
            float qa = s_q0[n][a];
            #pragma unroll
            for (int b = 0; b < Q0c; b++) s0 += qa * s_kv[e][b] * Wd0[a*8+b];
        }
        float s1 = 0.f;
        #pragma unroll
        for (int a = 0; a < Q1c; a++) {
            #pragma unroll
            for (int b = 0; b < Q1c; b++) {
                float d = s_q1[n][a*3+0]*s_kv[e][8+b*3+0]
                        + s_q1[n][a*3+1]*s_kv[e][8+b*3+1]
                        + s_q1[n][a*3+2]*s_kv[e][8+b*3+2];
                s1 += d * Wd1[a*4+b];
            }
        }
        s_logit[e] = (s0 + s1*0.5773502691896258f) * 0.11180339887498948f; // dnorm=1/sqrt(80)
    }
    __syncthreads();

    // ---- Phase F: per-node softmax over 8 edges ----
    if (tid < NPB) {
        int n = tid;
        float m = -1e30f;
        #pragma unroll
        for (int e = 0; e < 8; e++) m = fmaxf(m, s_logit[n*8+e]);
        float z[8]; float s = 0.f;
        #pragma unroll
        for (int e = 0; e < 8; e++) { z[e] = expf(s_logit[n*8+e]-m); s += z[e]; }
        float inv_s = 1.0f / s;
        #pragma unroll
        for (int e = 0; e < 8; e++) {
            float alpha = z[e]*inv_s * s_cut[n*8+e];
            s_we[n*8+e] = sqrtf(alpha + 1e-12f);
        }
    }
    __syncthreads();

    // ---- Phase G: weighted sum -> out ----
    if (tid < NPB*40) {
        int n = tid/40, c = tid%40;
        float acc = 0.f;
        #pragma unroll
        for (int e = 0; e < 8; e++) acc += s_we[n*8+e]*s_kv[n*8+e][20+c];
        out[(node0+n)*40 + c] = acc;
    }
}

extern "C" void kernel_launch(void* const* d_in, const int* in_sizes, int n_in,
                              void* d_out, int out_size, void* d_ws, size_t ws_size,
                              hipStream_t stream) {
    const float* f    = (const float*)d_in[0];
    const float* pos  = (const float*)d_in[1];
    const float* W1k  = (const float*)d_in[2];
    const float* W2k  = (const float*)d_in[3];
    const float* W1v  = (const float*)d_in[4];
    const float* W2v  = (const float*)d_in[5];
    const float* Wq0  = (const float*)d_in[6];
    const float* Wq1  = (const float*)d_in[7];
    const float* Wd0  = (const float*)d_in[8];
    const float* Wd1  = (const float*)d_in[9];
    // d_in[10] = batch (unused by reference math)
    const int*   esrc = (const int*)d_in[11];
    float* out = (float*)d_out;

    dim3 grid(NN / NPB);
    dim3 block(256);
    hipLaunchKernelGGL(se3_fused, grid, block, 0, stream,
                       f, pos, W1k, W2k, W1v, W2v, Wq0, Wq1, Wd0, Wd1, esrc, out);
}

// Round 10
// 505.120 us; speedup vs baseline: 1.2249x; 1.0043x over previous
//
#include <hip/hip_runtime.h>
#include <math.h>

// SE3Transformer fused kernel. R9: Phase C via MFMA 16x16x32 bf16 (split hi/lo,
// 3-product = fp32-level accuracy). W2 pre-transposed/split to bf16 in d_ws.
#define NN    20000
#define KEDGE 8
#define NBF   16
#define HID   64
#define A0c   16
#define A1c   8
#define Q0c   8
#define Q1c   4
#define WKC   288
#define WVC   576
#define TOTC  864    // 54 MFMA N-tiles of 16
#define EPB   16
#define NPB   2
#define WPAD  876    // s_wkv row pad: 876 mod 32 = 12 -> 2-way banks on D-write

typedef __attribute__((ext_vector_type(8))) short bf16x8;
typedef __attribute__((ext_vector_type(4))) float f32x4;

static __device__ __forceinline__ unsigned short f2bf_rne(float x) {
    unsigned int u = __float_as_uint(x);
    unsigned int lsb = (u >> 16) & 1u;
    u += 0x7fffu + lsb;
    return (unsigned short)(u >> 16);
}
static __device__ __forceinline__ float bf2f(unsigned short h) {
    return __uint_as_float(((unsigned int)h) << 16);
}

// Prep: W2T_hi/lo[j][k] (bf16, [864][64]) from W2k [64][288], W2v [64][576].
__global__ __launch_bounds__(256) void w2_prep(const float* __restrict__ W2k,
                                               const float* __restrict__ W2v,
                                               unsigned short* __restrict__ hi,
                                               unsigned short* __restrict__ lo) {
    int idx = blockIdx.x * 256 + threadIdx.x;      // 0 .. 55295
    int j = idx >> 6, k = idx & 63;
    float w = (j < WKC) ? W2k[k * WKC + j] : W2v[k * WVC + (j - WKC)];
    unsigned short h = f2bf_rne(w);
    hi[idx] = h;
    lo[idx] = f2bf_rne(w - bf2f(h));
}

__global__ __launch_bounds__(256, 2)
void se3_fused(const float* __restrict__ f,
               const float* __restrict__ pos,
               const float* __restrict__ W1k,
               const float* __restrict__ W1v,
               const float* __restrict__ Wq0,
               const float* __restrict__ Wq1,
               const float* __restrict__ Wd0,
               const float* __restrict__ Wd1,
               const int* __restrict__ esrc,
               const unsigned short* __restrict__ w2t_hi,
               const unsigned short* __restrict__ w2t_lo,
               float* __restrict__ out)
{
    const int tid   = threadIdx.x;
    const int e0    = blockIdx.x * EPB;
    const int node0 = blockIdx.x * NPB;

    __shared__ float s_fs0[EPB][A0c];
    __shared__ float s_fs1[EPB][A1c*3];
    __shared__ float s_dot[EPB][A1c];
    __shared__ float s_y1[EPB][4];
    __shared__ float s_basis[EPB][NBF];
    __shared__ float s_cut[EPB];
    __shared__ int   s_src[EPB];
    __shared__ float s_r[EPB];
    // A-operands for MFMA: [edge][hid] bf16 hi/lo, 16B-chunk XOR swizzle
    __shared__ __align__(16) unsigned short s_hk_hi[EPB][HID];
    __shared__ __align__(16) unsigned short s_hk_lo[EPB][HID];
    __shared__ __align__(16) unsigned short s_hv_hi[EPB][HID];
    __shared__ __align__(16) unsigned short s_hv_lo[EPB][HID];
    __shared__ float s_wkv[EPB][WPAD];
    __shared__ float s_kv[EPB][60];
    __shared__ float s_q0[NPB][Q0c];
    __shared__ float s_q1[NPB][Q1c*3];
    __shared__ float s_logit[EPB];
    __shared__ float s_we[EPB];

    // ---- Phase A1: per-edge geometry ----
    if (tid < EPB) {
        int e = tid;
        int src = esrc[e0 + e];
        int dst = node0 + (e >> 3);   // edge_dst = repeat(arange(N), K)
        s_src[e] = src;
        float dx = pos[src*3+0] - pos[dst*3+0];
        float dy = pos[src*3+1] - pos[dst*3+1];
        float dz = pos[src*3+2] - pos[dst*3+2];
        float r  = sqrtf(dx*dx + dy*dy + dz*dz + 1e-12f);
        s_r[e] = r;
        const float s3 = 1.7320508075688772f;
        float inv_r = 1.0f / r;
        s_y1[e][0] = s3*dx*inv_r;
        s_y1[e][1] = s3*dy*inv_r;
        s_y1[e][2] = s3*dz*inv_r;
        float xcut = 10.0f*(1.0f - r*(1.0f/3.5f));
        s_cut[e] = (xcut > 0.0f) ? expf(-1.0f/xcut) : 0.0f;
    }
    __syncthreads();

    // ---- Phase A2: basis, gather src features, queries ----
    {
        int e = tid >> 4, c = tid & 15;
        float r = s_r[e];
        const float step = 3.5f / 17.0f;
        float ctr = step * (float)(c + 1);
        float tt  = (r - ctr) * (1.0f/step);
        s_basis[e][c] = expf(-tt*tt) * (4.0f/1.12f);
        s_fs0[e][c]   = f[s_src[e]*40 + c];
    }
    for (int rep = 0; rep < 2; rep++) {
        int slot = rep*256 + tid;
        if (slot < EPB*24) {
            int e = slot/24, c = slot%24;
            s_fs1[e][c] = f[s_src[e]*40 + 16 + c];
        }
    }
    if (tid < NPB*Q0c) {
        int n = tid >> 3, q = tid & 7;
        const float* fn = f + (node0+n)*40;
        float acc = 0.f;
        #pragma unroll
        for (int a = 0; a < A0c; a++) acc += fn[a]*Wq0[a*Q0c+q];
        s_q0[n][q] = acc * 0.25f;
    }
    if (tid >= 64 && tid < 64 + NPB*Q1c*3) {
        int s = tid - 64;
        int n = s/12, qi = s%12, q = qi/3, i = qi%3;
        const float* fn = f + (node0+n)*40 + 16;
        float acc = 0.f;
        #pragma unroll
        for (int a = 0; a < A1c; a++) acc += fn[a*3+i]*Wq1[a*Q1c+q];
        s_q1[n][qi] = acc * 0.35355339059327373f;
    }
    __syncthreads();

    // ---- Phase B: dot11 + hidden vectors hk/hv -> bf16 hi/lo, swizzled ----
    if (tid < EPB*A1c) {
        int e = tid >> 3, a = tid & 7;
        float acc = s_fs1[e][a*3+0]*s_y1[e][0]
                  + s_fs1[e][a*3+1]*s_y1[e][1]
                  + s_fs1[e][a*3+2]*s_y1[e][2];
        s_dot[e][a] = acc * 0.5773502691896258f;
    }
    {
        int wid = tid >> 6, lane = tid & 63;
        for (int rep = 0; rep < 4; rep++) {
            int e = rep*4 + wid;
            float ak = 0.f, av = 0.f;
            #pragma unroll
            for (int nb = 0; nb < NBF; nb++) {
                float b = s_basis[e][nb];
                ak += b * W1k[nb*HID + lane];
                av += b * W1v[nb*HID + lane];
            }
            ak *= 0.25f; av *= 0.25f;
            ak = ak / (1.0f + expf(-ak));          // silu
            av = av / (1.0f + expf(-av));
            // swizzled element slot: 16B chunk (lane>>3) XOR'd with row
            int sw = (((lane>>3) ^ (e&7)) << 3) | (lane & 7);
            unsigned short khi = f2bf_rne(ak);
            s_hk_hi[e][sw] = khi;
            s_hk_lo[e][sw] = f2bf_rne(ak - bf2f(khi));
            unsigned short vhi = f2bf_rne(av);
            s_hv_hi[e][sw] = vhi;
            s_hv_lo[e][sw] = f2bf_rne(av - bf2f(vhi));
        }
    }
    __syncthreads();

    // ---- Phase C: wkv = (h @ W2)/8 via MFMA 16x16x32 bf16, 3-product split ----
    // A: lane holds h[m = lane&15][k = ks*32 + (lane>>4)*8 + j], j=0..7
    // B: lane holds W2[k][n = tile*16 + (lane&15)] from pre-transposed w2t
    // D: col = lane&15 (n), row = (lane>>4)*4 + reg (edge)
    {
        int lane = tid & 63;
        int wid  = tid >> 6;
        int er   = lane & 15;
        int kq   = lane >> 4;
        bf16x8 ak_hi[2], ak_lo[2], av_hi[2], av_lo[2];
        #pragma unroll
        for (int ks = 0; ks < 2; ks++) {
            int csw = (((ks*4 + kq) ^ (er & 7)) << 3);
            ak_hi[ks] = *(const bf16x8*)&s_hk_hi[er][csw];
            ak_lo[ks] = *(const bf16x8*)&s_hk_lo[er][csw];
            av_hi[ks] = *(const bf16x8*)&s_hv_hi[er][csw];
            av_lo[ks] = *(const bf16x8*)&s_hv_lo[er][csw];
        }
        // k-path tiles [0,18)
        for (int t = wid; t < 18; t += 4) {
            const unsigned short* bh = w2t_hi + (t*16 + er)*64 + kq*8;
            const unsigned short* bl = w2t_lo + (t*16 + er)*64 + kq*8;
            f32x4 acc = {0.f, 0.f, 0.f, 0.f};
            #pragma unroll
            for (int ks = 0; ks < 2; ks++) {
                bf16x8 bhi = *(const bf16x8*)(bh + ks*32);
                bf16x8 blo = *(const bf16x8*)(bl + ks*32);
                acc = __builtin_amdgcn_mfma_f32_16x16x32_bf16(ak_hi[ks], bhi, acc, 0,0,0);
                acc = __builtin_amdgcn_mfma_f32_16x16x32_bf16(ak_lo[ks], bhi, acc, 0,0,0);
                acc = __builtin_amdgcn_mfma_f32_16x16x32_bf16(ak_hi[ks], blo, acc, 0,0,0);
            }
            #pragma unroll
            for (int r = 0; r < 4; r++)
                s_wkv[kq*4 + r][t*16 + er] = acc[r] * 0.125f;
        }
        // v-path tiles [18,54), continue each wave's stride-4 sequence
        for (int t = 18 + ((wid + 2) & 3); t < 54; t += 4) {
            const unsigned short* bh = w2t_hi + (t*16 + er)*64 + kq*8;
            const unsigned short* bl = w2t_lo + (t*16 + er)*64 + kq*8;
            f32x4 acc = {0.f, 0.f, 0.f, 0.f};
            #pragma unroll
            for (int ks = 0; ks < 2; ks++) {
                bf16x8 bhi = *(const bf16x8*)(bh + ks*32);
                bf16x8 blo = *(const bf16x8*)(bl + ks*32);
                acc = __builtin_amdgcn_mfma_f32_16x16x32_bf16(av_hi[ks], bhi, acc, 0,0,0);
                acc = __builtin_amdgcn_mfma_f32_16x16x32_bf16(av_lo[ks], bhi, acc, 0,0,0);
                acc = __builtin_amdgcn_mfma_f32_16x16x32_bf16(av_hi[ks], blo, acc, 0,0,0);
            }
            #pragma unroll
            for (int r = 0; r < 4; r++)
                s_wkv[kq*4 + r][t*16 + er] = acc[r] * 0.125f;
        }
    }
    __syncthreads();

    // ---- Phase D: tensor product -> k0,k1,v0,v1 (60 outputs/edge) ----
    const float nrm = 0.2041241452319315f;   // 1/sqrt(A0+A1)
    for (int rep = 0; rep < 4; rep++) {
        int slot = rep*256 + tid;
        if (slot < EPB*60) {
            int e = slot/60, o = slot%60;
            const float* wr = &s_wkv[e][0];
            float val = 0.f;
            if (o < 8) {                       // k0[b]
                int b = o;
                #pragma unroll
                for (int a = 0; a < A0c; a++) val += s_fs0[e][a]*wr[a*8+b];
                #pragma unroll
                for (int a = 0; a < A1c; a++) val += s_dot[e][a]*wr[128+a*8+b];
            } else if (o < 20) {               // k1[b][i]
                int idx = o-8; int b = idx/3, i = idx%3;
                float t0 = 0.f, t1 = 0.f;
                #pragma unroll
                for (int a = 0; a < A0c; a++) t0 += s_fs0[e][a]*wr[192+a*4+b];
                #pragma unroll
                for (int a = 0; a < A1c; a++) t1 += s_fs1[e][a*3+i]*wr[256+a*4+b];
                val = t0*s_y1[e][i] + t1;
            } else if (o < 36) {               // v0[b]
                int b = o-20;
                #pragma unroll
                for (int a = 0; a < A0c; a++) val += s_fs0[e][a]*wr[288+a*16+b];
                #pragma unroll
                for (int a = 0; a < A1c; a++) val += s_dot[e][a]*wr[288+256+a*16+b];
            } else {                           // v1[b][i]
                int idx = o-36; int b = idx/3, i = idx%3;
                float t0 = 0.f, t1 = 0.f;
                #pragma unroll
                for (int a = 0; a < A0c; a++) t0 += s_fs0[e][a]*wr[288+384+a*8+b];
                #pragma unroll
                for (int a = 0; a < A1c; a++) t1 += s_fs1[e][a*3+i]*wr[288+512+a*8+b];
                val = t0*s_y1[e][i] + t1;
            }
            s_kv[e][o] = val * nrm;
        }
    }
    __syncthreads();

    // ---- Phase E: logits ----
    if (tid < EPB) {
        int e = tid, n = e >> 3;
        float s0 = 0.f;
        #pragma unroll
        for (int a = 0; a < Q0c; a++) {
            float qa = s_q0[n][a];
            #pragma unroll
            for (int b = 0; b < Q0c; b++) s0 += qa * s_kv[e][b] * Wd0[a*8+b];
        }
        float s1 = 0.f;
        #pragma unroll
        for (int a = 0; a < Q1c; a++) {
            #pragma unroll
            for (int b = 0; b < Q1c; b++) {
                float d = s_q1[n][a*3+0]*s_kv[e][8+b*3+0]
                        + s_q1[n][a*3+1]*s_kv[e][8+b*3+1]
                        + s_q1[n][a*3+2]*s_kv[e][8+b*3+2];
                s1 += d * Wd1[a*4+b];
            }
        }
        s_logit[e] = (s0 + s1*0.5773502691896258f) * 0.11180339887498948f;
    }
    __syncthreads();

    // ---- Phase F: per-node softmax over 8 edges ----
    if (tid < NPB) {
        int n = tid;
        float m = -1e30f;
        #pragma unroll
        for (int e = 0; e < 8; e++) m = fmaxf(m, s_logit[n*8+e]);
        float z[8]; float s = 0.f;
        #pragma unroll
        for (int e = 0; e < 8; e++) { z[e] = expf(s_logit[n*8+e]-m); s += z[e]; }
        float inv_s = 1.0f / s;
        #pragma unroll
        for (int e = 0; e < 8; e++) {
            float alpha = z[e]*inv_s * s_cut[n*8+e];
            s_we[n*8+e] = sqrtf(alpha + 1e-12f);
        }
    }
    __syncthreads();

    // ---- Phase G: weighted sum -> out ----
    if (tid < NPB*40) {
        int n = tid/40, c = tid%40;
        float acc = 0.f;
        #pragma unroll
        for (int e = 0; e < 8; e++) acc += s_we[n*8+e]*s_kv[n*8+e][20+c];
        out[(node0+n)*40 + c] = acc;
    }
}

extern "C" void kernel_launch(void* const* d_in, const int* in_sizes, int n_in,
                              void* d_out, int out_size, void* d_ws, size_t ws_size,
                              hipStream_t stream) {
    const float* f    = (const float*)d_in[0];
    const float* pos  = (const float*)d_in[1];
    const float* W1k  = (const float*)d_in[2];
    const float* W2k  = (const float*)d_in[3];
    const float* W1v  = (const float*)d_in[4];
    const float* W2v  = (const float*)d_in[5];
    const float* Wq0  = (const float*)d_in[6];
    const float* Wq1  = (const float*)d_in[7];
    const float* Wd0  = (const float*)d_in[8];
    const float* Wd1  = (const float*)d_in[9];
    const int*   esrc = (const int*)d_in[11];
    float* out = (float*)d_out;

    unsigned short* w2t_hi = (unsigned short*)d_ws;
    unsigned short* w2t_lo = w2t_hi + TOTC*HID;   // 55296 elems each

    hipLaunchKernelGGL(w2_prep, dim3(TOTC*HID/256), dim3(256), 0, stream,
                       W2k, W2v, w2t_hi, w2t_lo);
    hipLaunchKernelGGL(se3_fused, dim3(NN/NPB), dim3(256), 0, stream,
                       f, pos, W1k, W1v, Wq0, Wq1, Wd0, Wd1, esrc,
                       w2t_hi, w2t_lo, out);
}

// Round 13
// 381.377 us; speedup vs baseline: 1.6223x; 1.3245x over previous
//
#include <hip/hip_runtime.h>
#include <math.h>

// SE3Transformer fused kernel. R11: bf16 s_wkv -> 43.5 KB LDS -> 3 blocks/CU;
// merged phases (5 barriers); shuffle softmax; uniform Phase D mapping.
// Phase C: MFMA 16x16x32 bf16 split hi/lo (3-product), W2T prepped in d_ws.
#define NN    20000
#define NBF   16
#define HID   64
#define A0c   16
#define A1c   8
#define Q0c   8
#define Q1c   4
#define WKC   288
#define WVC   576
#define TOTC  864    // 54 MFMA N-tiles of 16
#define EPB   16
#define NPB   2
#define WP2   868    // bf16 wkv row pad: 4-row stride = 8 banks, edge stride = 18

typedef __attribute__((ext_vector_type(8))) short bf16x8;
typedef __attribute__((ext_vector_type(4))) float f32x4;

static __device__ __forceinline__ unsigned short f2bf_rne(float x) {
    unsigned int u = __float_as_uint(x);
    unsigned int lsb = (u >> 16) & 1u;
    u += 0x7fffu + lsb;
    return (unsigned short)(u >> 16);
}
static __device__ __forceinline__ float bf2f(unsigned short h) {
    return __uint_as_float(((unsigned int)h) << 16);
}

// Prep: W2T_hi/lo[j][k] (bf16, [864][64]) from W2k [64][288], W2v [64][576].
__global__ __launch_bounds__(256) void w2_prep(const float* __restrict__ W2k,
                                               const float* __restrict__ W2v,
                                               unsigned short* __restrict__ hi,
                                               unsigned short* __restrict__ lo) {
    int idx = blockIdx.x * 256 + threadIdx.x;      // 0 .. 55295
    int j = idx >> 6, k = idx & 63;
    float w = (j < WKC) ? W2k[k * WKC + j] : W2v[k * WVC + (j - WKC)];
    unsigned short h = f2bf_rne(w);
    hi[idx] = h;
    lo[idx] = f2bf_rne(w - bf2f(h));
}

__global__ __launch_bounds__(256, 3)
void se3_fused(const float* __restrict__ f,
               const float* __restrict__ pos,
               const float* __restrict__ W1k,
               const float* __restrict__ W1v,
               const float* __restrict__ Wq0,
               const float* __restrict__ Wq1,
               const float* __restrict__ Wd0,
               const float* __restrict__ Wd1,
               const int* __restrict__ esrc,
               const unsigned short* __restrict__ w2t_hi,
               const unsigned short* __restrict__ w2t_lo,
               float* __restrict__ out)
{
    const int tid   = threadIdx.x;
    const int e0    = blockIdx.x * EPB;
    const int node0 = blockIdx.x * NPB;

    __shared__ float s_fs0[EPB][A0c];
    __shared__ float s_fs1[EPB][A1c*3];
    __shared__ float s_dot[EPB][A1c];
    __shared__ float s_y1[EPB][4];
    __shared__ float s_basis[EPB][NBF];
    __shared__ float s_cut[EPB];
    __shared__ __align__(16) unsigned short s_hk_hi[EPB][HID];
    __shared__ __align__(16) unsigned short s_hk_lo[EPB][HID];
    __shared__ __align__(16) unsigned short s_hv_hi[EPB][HID];
    __shared__ __align__(16) unsigned short s_hv_lo[EPB][HID];
    __shared__ unsigned short s_wkv[EPB][WP2];   // bf16 wkv
    __shared__ float s_kv[EPB][60];
    __shared__ float s_q0[NPB][Q0c];
    __shared__ float s_q1[NPB][Q1c*3];
    __shared__ float s_we[EPB];

    // ---- Phase A: geometry + basis + gathers + queries (one phase) ----
    {
        int e = tid >> 4, c = tid & 15;
        int src = esrc[e0 + e];                  // broadcast within 16-lane group
        int dst = node0 + (e >> 3);
        float dx = pos[src*3+0] - pos[dst*3+0];
        float dy = pos[src*3+1] - pos[dst*3+1];
        float dz = pos[src*3+2] - pos[dst*3+2];
        float r  = sqrtf(dx*dx + dy*dy + dz*dz + 1e-12f);
        const float step = 3.5f / 17.0f;
        float ctr = step * (float)(c + 1);
        float tt  = (r - ctr) * (1.0f/step);
        s_basis[e][c] = expf(-tt*tt) * (4.0f/1.12f);
        s_fs0[e][c]   = f[src*40 + c];
        s_fs1[e][c]   = f[src*40 + 16 + c];
        if (c < 8) s_fs1[e][16 + c] = f[src*40 + 32 + c];
        if (c == 0) {
            const float s3 = 1.7320508075688772f;
            float inv_r = 1.0f / r;
            s_y1[e][0] = s3*dx*inv_r;
            s_y1[e][1] = s3*dy*inv_r;
            s_y1[e][2] = s3*dz*inv_r;
            float xcut = 10.0f*(1.0f - r*(1.0f/3.5f));
            s_cut[e] = (xcut > 0.0f) ? expf(-1.0f/xcut) : 0.0f;
        }
        if (tid >= 240) {                        // q0 = f0 @ Wq0 / 4
            int idx = tid - 240, n = idx >> 3, q = idx & 7;
            const float* fn = f + (node0+n)*40;
            float acc = 0.f;
            #pragma unroll
            for (int a = 0; a < A0c; a++) acc += fn[a]*Wq0[a*Q0c+q];
            s_q0[n][q] = acc * 0.25f;
        }
        if (tid >= 192 && tid < 216) {           // q1 = einsum(f1,Wq1)/sqrt(8)
            int idx = tid - 192, n = idx/12, qi = idx%12, q = qi/3, i = qi%3;
            const float* fn = f + (node0+n)*40 + 16;
            float acc = 0.f;
            #pragma unroll
            for (int a = 0; a < A1c; a++) acc += fn[a*3+i]*Wq1[a*Q1c+q];
            s_q1[n][qi] = acc * 0.35355339059327373f;
        }
    }
    __syncthreads();

    // ---- Phase B: dot11 + hidden vectors hk/hv -> bf16 hi/lo, swizzled ----
    if (tid < EPB*A1c) {
        int e = tid >> 3, a = tid & 7;
        float acc = s_fs1[e][a*3+0]*s_y1[e][0]
                  + s_fs1[e][a*3+1]*s_y1[e][1]
                  + s_fs1[e][a*3+2]*s_y1[e][2];
        s_dot[e][a] = acc * 0.5773502691896258f;
    }
    {
        int wid = tid >> 6, lane = tid & 63;
        for (int rep = 0; rep < 4; rep++) {
            int e = rep*4 + wid;
            float ak = 0.f, av = 0.f;
            #pragma unroll
            for (int nb = 0; nb < NBF; nb++) {
                float b = s_basis[e][nb];
                ak += b * W1k[nb*HID + lane];
                av += b * W1v[nb*HID + lane];
            }
            ak *= 0.25f; av *= 0.25f;
            ak = ak / (1.0f + expf(-ak));          // silu
            av = av / (1.0f + expf(-av));
            int sw = (((lane>>3) ^ (e&7)) << 3) | (lane & 7);
            unsigned short khi = f2bf_rne(ak);
            s_hk_hi[e][sw] = khi;
            s_hk_lo[e][sw] = f2bf_rne(ak - bf2f(khi));
            unsigned short vhi = f2bf_rne(av);
            s_hv_hi[e][sw] = vhi;
            s_hv_lo[e][sw] = f2bf_rne(av - bf2f(vhi));
        }
    }
    __syncthreads();

    // ---- Phase C: wkv = (h @ W2)/8 via MFMA 16x16x32 bf16, 3-product split ----
    {
        int lane = tid & 63;
        int wid  = tid >> 6;
        int er   = lane & 15;
        int kq   = lane >> 4;
        bf16x8 ak_hi[2], ak_lo[2], av_hi[2], av_lo[2];
        #pragma unroll
        for (int ks = 0; ks < 2; ks++) {
            int csw = (((ks*4 + kq) ^ (er & 7)) << 3);
            ak_hi[ks] = *(const bf16x8*)&s_hk_hi[er][csw];
            ak_lo[ks] = *(const bf16x8*)&s_hk_lo[er][csw];
            av_hi[ks] = *(const bf16x8*)&s_hv_hi[er][csw];
            av_lo[ks] = *(const bf16x8*)&s_hv_lo[er][csw];
        }
        for (int t = wid; t < 18; t += 4) {        // k-path tiles
            const unsigned short* bh = w2t_hi + (t*16 + er)*64 + kq*8;
            const unsigned short* bl = w2t_lo + (t*16 + er)*64 + kq*8;
            f32x4 acc = {0.f, 0.f, 0.f, 0.f};
            #pragma unroll
            for (int ks = 0; ks < 2; ks++) {
                bf16x8 bhi = *(const bf16x8*)(bh + ks*32);
                bf16x8 blo = *(const bf16x8*)(bl + ks*32);
                acc = __builtin_amdgcn_mfma_f32_16x16x32_bf16(ak_hi[ks], bhi, acc, 0,0,0);
                acc = __builtin_amdgcn_mfma_f32_16x16x32_bf16(ak_lo[ks], bhi, acc, 0,0,0);
                acc = __builtin_amdgcn_mfma_f32_16x16x32_bf16(ak_hi[ks], blo, acc, 0,0,0);
            }
            #pragma unroll
            for (int r = 0; r < 4; r++)
                s_wkv[kq*4 + r][t*16 + er] = f2bf_rne(acc[r] * 0.125f);
        }
        for (int t = 18 + ((wid + 2) & 3); t < 54; t += 4) {   // v-path tiles
            const unsigned short* bh = w2t_hi + (t*16 + er)*64 + kq*8;
            const unsigned short* bl = w2t_lo + (t*16 + er)*64 + kq*8;
            f32x4 acc = {0.f, 0.f, 0.f, 0.f};
            #pragma unroll
            for (int ks = 0; ks < 2; ks++) {
                bf16x8 bhi = *(const bf16x8*)(bh + ks*32);
                bf16x8 blo = *(const bf16x8*)(bl + ks*32);
                acc = __builtin_amdgcn_mfma_f32_16x16x32_bf16(av_hi[ks], bhi, acc, 0,0,0);
                acc = __builtin_amdgcn_mfma_f32_16x16x32_bf16(av_lo[ks], bhi, acc, 0,0,0);
                acc = __builtin_amdgcn_mfma_f32_16x16x32_bf16(av_hi[ks], blo, acc, 0,0,0);
            }
            #pragma unroll
            for (int r = 0; r < 4; r++)
                s_wkv[kq*4 + r][t*16 + er] = f2bf_rne(acc[r] * 0.125f);
        }
    }
    __syncthreads();

    // ---- Phase D: tensor product, thread (e, j) -> outputs j, j+16, j+32, j+48
    {
        const float nrm = 0.2041241452319315f;   // 1/sqrt(A0+A1)
        int e = tid >> 4, j = tid & 15;
        const unsigned short* wr = &s_wkv[e][0];
        const float* fs0 = &s_fs0[e][0];
        const float* fs1 = &s_fs1[e][0];
        const float* dt  = &s_dot[e][0];
        const float* y1  = &s_y1[e][0];
        // rep 0: o = j  (k0 for o<8, k1 for 8..15)
        {
            int o = j; float val;
            if (o < 8) {
                int b = o; val = 0.f;
                #pragma unroll
                for (int a = 0; a < A0c; a++) val += fs0[a]*bf2f(wr[a*8+b]);
                #pragma unroll
                for (int a = 0; a < A1c; a++) val += dt[a]*bf2f(wr[128+a*8+b]);
            } else {
                int idx = o-8, b = idx/3, i = idx%3;
                float t0 = 0.f, t1 = 0.f;
                #pragma unroll
                for (int a = 0; a < A0c; a++) t0 += fs0[a]*bf2f(wr[192+a*4+b]);
                #pragma unroll
                for (int a = 0; a < A1c; a++) t1 += fs1[a*3+i]*bf2f(wr[256+a*4+b]);
                val = t0*y1[i] + t1;
            }
            s_kv[e][o] = val * nrm;
        }
        // rep 1: o = 16+j  (k1 for o<20, v0 for 20..31)
        {
            int o = 16 + j; float val;
            if (o < 20) {
                int idx = o-8, b = idx/3, i = idx%3;
                float t0 = 0.f, t1 = 0.f;
                #pragma unroll
                for (int a = 0; a < A0c; a++) t0 += fs0[a]*bf2f(wr[192+a*4+b]);
                #pragma unroll
                for (int a = 0; a < A1c; a++) t1 += fs1[a*3+i]*bf2f(wr[256+a*4+b]);
                val = t0*y1[i] + t1;
            } else {
                int b = o-20; val = 0.f;
                #pragma unroll
                for (int a = 0; a < A0c; a++) val += fs0[a]*bf2f(wr[288+a*16+b]);
                #pragma unroll
                for (int a = 0; a < A1c; a++) val += dt[a]*bf2f(wr[288+256+a*16+b]);
            }
            s_kv[e][o] = val * nrm;
        }
        // rep 2: o = 32+j  (v0 for o<36, v1 for 36..47)
        {
            int o = 32 + j; float val;
            if (o < 36) {
                int b = o-20; val = 0.f;
                #pragma unroll
                for (int a = 0; a < A0c; a++) val += fs0[a]*bf2f(wr[288+a*16+b]);
                #pragma unroll
                for (int a = 0; a < A1c; a++) val += dt[a]*bf2f(wr[288+256+a*16+b]);
            } else {
                int idx = o-36, b = idx/3, i = idx%3;
                float t0 = 0.f, t1 = 0.f;
                #pragma unroll
                for (int a = 0; a < A0c; a++) t0 += fs0[a]*bf2f(wr[288+384+a*8+b]);
                #pragma unroll
                for (int a = 0; a < A1c; a++) t1 += fs1[a*3+i]*bf2f(wr[288+512+a*8+b]);
                val = t0*y1[i] + t1;
            }
            s_kv[e][o] = val * nrm;
        }
        // rep 3: o = 48+j (v1; j<12)
        if (j < 12) {
            int o = 48 + j;
            int idx = o-36, b = idx/3, i = idx%3;
            float t0 = 0.f, t1 = 0.f;
            #pragma unroll
            for (int a = 0; a < A0c; a++) t0 += fs0[a]*bf2f(wr[288+384+a*8+b]);
            #pragma unroll
            for (int a = 0; a < A1c; a++) t1 += fs1[a*3+i]*bf2f(wr[288+512+a*8+b]);
            s_kv[e][o] = (t0*y1[i] + t1) * nrm;
        }
    }
    __syncthreads();

    // ---- Phase EF: logits + softmax (wave 0, width-8 shuffles) ----
    if (tid < 64) {
        int e = tid & 15, n = e >> 3;
        float s0 = 0.f;
        #pragma unroll
        for (int a = 0; a < Q0c; a++) {
            float qa = s_q0[n][a];
            #pragma unroll
            for (int b = 0; b < Q0c; b++) s0 += qa * s_kv[e][b] * Wd0[a*8+b];
        }
        float s1 = 0.f;
        #pragma unroll
        for (int a = 0; a < Q1c; a++) {
            #pragma unroll
            for (int b = 0; b < Q1c; b++) {
                float d = s_q1[n][a*3+0]*s_kv[e][8+b*3+0]
                        + s_q1[n][a*3+1]*s_kv[e][8+b*3+1]
                        + s_q1[n][a*3+2]*s_kv[e][8+b*3+2];
                s1 += d * Wd1[a*4+b];
            }
        }
        float L = (s0 + s1*0.5773502691896258f) * 0.11180339887498948f;
        float m = L;
        m = fmaxf(m, __shfl_xor(m, 1, 8));
        m = fmaxf(m, __shfl_xor(m, 2, 8));
        m = fmaxf(m, __shfl_xor(m, 4, 8));
        float z = expf(L - m);
        float ssum = z;
        ssum += __shfl_xor(ssum, 1, 8);
        ssum += __shfl_xor(ssum, 2, 8);
        ssum += __shfl_xor(ssum, 4, 8);
        float alpha = z / ssum * s_cut[e];
        if (tid < 16) s_we[e] = sqrtf(alpha + 1e-12f);
    }
    __syncthreads();

    // ---- Phase G: weighted sum -> out ----
    if (tid < NPB*40) {
        int n = tid/40, c = tid%40;
        float acc = 0.f;
        #pragma unroll
        for (int e = 0; e < 8; e++) acc += s_we[n*8+e]*s_kv[n*8+e][20+c];
        out[(node0+n)*40 + c] = acc;
    }
}

extern "C" void kernel_launch(void* const* d_in, const int* in_sizes, int n_in,
                              void* d_out, int out_size, void* d_ws, size_t ws_size,
                              hipStream_t stream) {
    const float* f    = (const float*)d_in[0];
    const float* pos  = (const float*)d_in[1];
    const float* W1k  = (const float*)d_in[2];
    const float* W2k  = (const float*)d_in[3];
    const float* W1v  = (const float*)d_in[4];
    const float* W2v  = (const float*)d_in[5];
    const float* Wq0  = (const float*)d_in[6];
    const float* Wq1  = (const float*)d_in[7];
    const float* Wd0  = (const float*)d_in[8];
    const float* Wd1  = (const float*)d_in[9];
    const int*   esrc = (const int*)d_in[11];
    float* out = (float*)d_out;

    unsigned short* w2t_hi = (unsigned short*)d_ws;
    unsigned short* w2t_lo = w2t_hi + TOTC*HID;   // 55296 elems each

    hipLaunchKernelGGL(w2_prep, dim3(TOTC*HID/256), dim3(256), 0, stream,
                       W2k, W2v, w2t_hi, w2t_lo);
    hipLaunchKernelGGL(se3_fused, dim3(NN/NPB), dim3(256), 0, stream,
                       f, pos, W1k, W1v, Wq0, Wq1, Wd0, Wd1, esrc,
                       w2t_hi, w2t_lo, out);
}

// Round 14
// 215.966 us; speedup vs baseline: 2.8649x; 1.7659x over previous
//
#include <hip/hip_runtime.h>
#include <math.h>

// SE3Transformer fused kernel. R14: 4 blocks/CU (s_kv unioned over hk/hv staging,
// LDS 40.6KB); Phase-C software prefetch with tile-contiguous W2T layout;
// W1 loads hoisted. Phase C: MFMA 16x16x32 bf16 split hi/lo (3-product).
#define NN    20000
#define NBF   16
#define HID   64
#define A0c   16
#define A1c   8
#define Q0c   8
#define Q1c   4
#define WKC   288
#define WVC   576
#define TOTC  864    // 54 MFMA N-tiles of 16
#define EPB   16
#define NPB   2
#define WP2   868    // bf16 wkv row pad

typedef __attribute__((ext_vector_type(8))) short bf16x8;
typedef __attribute__((ext_vector_type(4))) float f32x4;

static __device__ __forceinline__ unsigned short f2bf_rne(float x) {
    unsigned int u = __float_as_uint(x);
    unsigned int lsb = (u >> 16) & 1u;
    u += 0x7fffu + lsb;
    return (unsigned short)(u >> 16);
}
static __device__ __forceinline__ float bf2f(unsigned short h) {
    return __uint_as_float(((unsigned int)h) << 16);
}

// Prep: tile-contiguous B operands. idx = ((t*2+ks)*64 + kq*16 + er)*8 + j
// holds W2[k = ks*32+kq*8+j][n = t*16+er], so each wave's 16B/lane load of a
// (tile, ks) slice is one contiguous 1KB segment.
__global__ __launch_bounds__(256) void w2_prep(const float* __restrict__ W2k,
                                               const float* __restrict__ W2v,
                                               unsigned short* __restrict__ hi,
                                               unsigned short* __restrict__ lo) {
    int idx = blockIdx.x * 256 + threadIdx.x;      // 0 .. 55295
    int j  = idx & 7;
    int er = (idx >> 3) & 15;
    int kq = (idx >> 7) & 3;
    int ks = (idx >> 9) & 1;
    int t  = idx >> 10;
    int k = ks*32 + kq*8 + j;
    int n = t*16 + er;
    float w = (n < WKC) ? W2k[k * WKC + n] : W2v[k * WVC + (n - WKC)];
    unsigned short h = f2bf_rne(w);
    hi[idx] = h;
    lo[idx] = f2bf_rne(w - bf2f(h));
}

union HkKv {
    struct {
        unsigned short hk_hi[EPB][HID];
        unsigned short hk_lo[EPB][HID];
        unsigned short hv_hi[EPB][HID];
        unsigned short hv_lo[EPB][HID];
    } h;                                   // live: Phase B write -> Phase C reg load
    float kv[EPB][60];                     // live: Phase D write -> Phase G
};

#define MFMA3(AH, AL, B_HI, B_LO, ACC) \
    ACC = __builtin_amdgcn_mfma_f32_16x16x32_bf16(AH, B_HI, ACC, 0,0,0); \
    ACC = __builtin_amdgcn_mfma_f32_16x16x32_bf16(AL, B_HI, ACC, 0,0,0); \
    ACC = __builtin_amdgcn_mfma_f32_16x16x32_bf16(AH, B_LO, ACC, 0,0,0);

__global__ __launch_bounds__(256, 4)
void se3_fused(const float* __restrict__ f,
               const float* __restrict__ pos,
               const float* __restrict__ W1k,
               const float* __restrict__ W1v,
               const float* __restrict__ Wq0,
               const float* __restrict__ Wq1,
               const float* __restrict__ Wd0,
               const float* __restrict__ Wd1,
               const int* __restrict__ esrc,
               const unsigned short* __restrict__ w2t_hi,
               const unsigned short* __restrict__ w2t_lo,
               float* __restrict__ out)
{
    const int tid   = threadIdx.x;
    const int e0    = blockIdx.x * EPB;
    const int node0 = blockIdx.x * NPB;

    __shared__ float s_fs0[EPB][A0c];
    __shared__ float s_fs1[EPB][A1c*3];
    __shared__ float s_dot[EPB][A1c];
    __shared__ float s_y1[EPB][4];
    __shared__ float s_basis[EPB][NBF];
    __shared__ float s_cut[EPB];
    __shared__ __align__(16) HkKv s_u;
    __shared__ unsigned short s_wkv[EPB][WP2];   // bf16 wkv
    __shared__ float s_q0[NPB][Q0c];
    __shared__ float s_q1[NPB][Q1c*3];
    __shared__ float s_we[EPB];

    // ---- Phase A: geometry + basis + gathers + queries (one phase) ----
    {
        int e = tid >> 4, c = tid & 15;
        int src = esrc[e0 + e];
        int dst = node0 + (e >> 3);              // edge_dst = repeat(arange(N), K)
        float dx = pos[src*3+0] - pos[dst*3+0];
        float dy = pos[src*3+1] - pos[dst*3+1];
        float dz = pos[src*3+2] - pos[dst*3+2];
        float r  = sqrtf(dx*dx + dy*dy + dz*dz + 1e-12f);
        const float step = 3.5f / 17.0f;
        float ctr = step * (float)(c + 1);
        float tt  = (r - ctr) * (1.0f/step);
        s_basis[e][c] = expf(-tt*tt) * (4.0f/1.12f);
        s_fs0[e][c]   = f[src*40 + c];
        s_fs1[e][c]   = f[src*40 + 16 + c];
        if (c < 8) s_fs1[e][16 + c] = f[src*40 + 32 + c];
        if (c == 0) {
            const float s3 = 1.7320508075688772f;
            float inv_r = 1.0f / r;
            s_y1[e][0] = s3*dx*inv_r;
            s_y1[e][1] = s3*dy*inv_r;
            s_y1[e][2] = s3*dz*inv_r;
            float xcut = 10.0f*(1.0f - r*(1.0f/3.5f));
            s_cut[e] = (xcut > 0.0f) ? expf(-1.0f/xcut) : 0.0f;
        }
        if (tid >= 240) {                        // q0 = f0 @ Wq0 / 4
            int idx = tid - 240, n = idx >> 3, q = idx & 7;
            const float* fn = f + (node0+n)*40;
            float acc = 0.f;
            #pragma unroll
            for (int a = 0; a < A0c; a++) acc += fn[a]*Wq0[a*Q0c+q];
            s_q0[n][q] = acc * 0.25f;
        }
        if (tid >= 192 && tid < 216) {           // q1 = einsum(f1,Wq1)/sqrt(8)
            int idx = tid - 192, n = idx/12, qi = idx%12, q = qi/3, i = qi%3;
            const float* fn = f + (node0+n)*40 + 16;
            float acc = 0.f;
            #pragma unroll
            for (int a = 0; a < A1c; a++) acc += fn[a*3+i]*Wq1[a*Q1c+q];
            s_q1[n][qi] = acc * 0.35355339059327373f;
        }
    }
    __syncthreads();

    // ---- Phase B: dot11 + hidden vectors hk/hv -> bf16 hi/lo, swizzled ----
    if (tid < EPB*A1c) {
        int e = tid >> 3, a = tid & 7;
        float acc = s_fs1[e][a*3+0]*s_y1[e][0]
                  + s_fs1[e][a*3+1]*s_y1[e][1]
                  + s_fs1[e][a*3+2]*s_y1[e][2];
        s_dot[e][a] = acc * 0.5773502691896258f;
    }
    {
        int wid = tid >> 6, lane = tid & 63;
        float w1k_r[NBF], w1v_r[NBF];            // hoisted: rep-invariant
        #pragma unroll
        for (int nb = 0; nb < NBF; nb++) {
            w1k_r[nb] = W1k[nb*HID + lane];
            w1v_r[nb] = W1v[nb*HID + lane];
        }
        for (int rep = 0; rep < 4; rep++) {
            int e = rep*4 + wid;
            float ak = 0.f, av = 0.f;
            #pragma unroll
            for (int nb = 0; nb < NBF; nb++) {
                float b = s_basis[e][nb];
                ak += b * w1k_r[nb];
                av += b * w1v_r[nb];
            }
            ak *= 0.25f; av *= 0.25f;
            ak = ak / (1.0f + expf(-ak));          // silu
            av = av / (1.0f + expf(-av));
            int sw = (((lane>>3) ^ (e&7)) << 3) | (lane & 7);
            unsigned short khi = f2bf_rne(ak);
            s_u.h.hk_hi[e][sw] = khi;
            s_u.h.hk_lo[e][sw] = f2bf_rne(ak - bf2f(khi));
            unsigned short vhi = f2bf_rne(av);
            s_u.h.hv_hi[e][sw] = vhi;
            s_u.h.hv_lo[e][sw] = f2bf_rne(av - bf2f(vhi));
        }
    }
    __syncthreads();

    // ---- Phase C: wkv = (h @ W2)/8 via MFMA, software-prefetched B tiles ----
    // A: lane holds h[m = lane&15][k = ks*32 + (lane>>4)*8 + j]
    // B: tile-contiguous w2t, lane load = 16B at ((t*2+ks)*64 + lane)*8
    // D: col(n) = lane&15, row(edge) = (lane>>4)*4 + reg
    {
        int lane = tid & 63;
        int wid  = tid >> 6;
        int er   = lane & 15;
        int kq   = lane >> 4;
        bf16x8 ak_hi[2], ak_lo[2], av_hi[2], av_lo[2];
        #pragma unroll
        for (int ks = 0; ks < 2; ks++) {
            int csw = (((ks*4 + kq) ^ (er & 7)) << 3);
            ak_hi[ks] = *(const bf16x8*)&s_u.h.hk_hi[er][csw];
            ak_lo[ks] = *(const bf16x8*)&s_u.h.hk_lo[er][csw];
            av_hi[ks] = *(const bf16x8*)&s_u.h.hv_hi[er][csw];
            av_lo[ks] = *(const bf16x8*)&s_u.h.hv_lo[er][csw];
        }
        const unsigned short* bp_hi = w2t_hi + wid*1024 + lane*8;
        const unsigned short* bp_lo = w2t_lo + wid*1024 + lane*8;
        bf16x8 pb0 = *(const bf16x8*)(bp_hi);
        bf16x8 pb1 = *(const bf16x8*)(bp_hi + 512);
        bf16x8 pb2 = *(const bf16x8*)(bp_lo);
        bf16x8 pb3 = *(const bf16x8*)(bp_lo + 512);
        for (int t = wid; t < 54; t += 4) {
            bf16x8 cb0 = pb0, cb1 = pb1, cb2 = pb2, cb3 = pb3;
            if (t + 4 < 54) {                     // prefetch next tile
                bp_hi += 4096; bp_lo += 4096;
                pb0 = *(const bf16x8*)(bp_hi);
                pb1 = *(const bf16x8*)(bp_hi + 512);
                pb2 = *(const bf16x8*)(bp_lo);
                pb3 = *(const bf16x8*)(bp_lo + 512);
            }
            f32x4 acc = {0.f, 0.f, 0.f, 0.f};
            if (t < 18) {                         // k-path (wave-uniform branch)
                MFMA3(ak_hi[0], ak_lo[0], cb0, cb2, acc);
                MFMA3(ak_hi[1], ak_lo[1], cb1, cb3, acc);
            } else {                              // v-path
                MFMA3(av_hi[0], av_lo[0], cb0, cb2, acc);
                MFMA3(av_hi[1], av_lo[1], cb1, cb3, acc);
            }
            #pragma unroll
            for (int r = 0; r < 4; r++)
                s_wkv[kq*4 + r][t*16 + er] = f2bf_rne(acc[r] * 0.125f);
        }
    }
    __syncthreads();

    // ---- Phase D: tensor product, thread (e, j) -> outputs j, j+16, j+32, j+48
    {
        const float nrm = 0.2041241452319315f;   // 1/sqrt(A0+A1)
        int e = tid >> 4, j = tid & 15;
        const unsigned short* wr = &s_wkv[e][0];
        const float* fs0 = &s_fs0[e][0];
        const float* fs1 = &s_fs1[e][0];
        const float* dt  = &s_dot[e][0];
        const float* y1  = &s_y1[e][0];
        // rep 0: o = j  (k0 for o<8, k1 for 8..15)
        {
            int o = j; float val;
            if (o < 8) {
                int b = o; val = 0.f;
                #pragma unroll
                for (int a = 0; a < A0c; a++) val += fs0[a]*bf2f(wr[a*8+b]);
                #pragma unroll
                for (int a = 0; a < A1c; a++) val += dt[a]*bf2f(wr[128+a*8+b]);
            } else {
                int idx = o-8, b = idx/3, i = idx%3;
                float t0 = 0.f, t1 = 0.f;
                #pragma unroll
                for (int a = 0; a < A0c; a++) t0 += fs0[a]*bf2f(wr[192+a*4+b]);
                #pragma unroll
                for (int a = 0; a < A1c; a++) t1 += fs1[a*3+i]*bf2f(wr[256+a*4+b]);
                val = t0*y1[i] + t1;
            }
            s_u.kv[e][o] = val * nrm;
        }
        // rep 1: o = 16+j  (k1 for o<20, v0 for 20..31)
        {
            int o = 16 + j; float val;
            if (o < 20) {
                int idx = o-8, b = idx/3, i = idx%3;
                float t0 = 0.f, t1 = 0.f;
                #pragma unroll
                for (int a = 0; a < A0c; a++) t0 += fs0[a]*bf2f(wr[192+a*4+b]);
                #pragma unroll
                for (int a = 0; a < A1c; a++) t1 += fs1[a*3+i]*bf2f(wr[256+a*4+b]);
                val = t0*y1[i] + t1;
            } else {
                int b = o-20; val = 0.f;
                #pragma unroll
                for (int a = 0; a < A0c; a++) val += fs0[a]*bf2f(wr[288+a*16+b]);
                #pragma unroll
                for (int a = 0; a < A1c; a++) val += dt[a]*bf2f(wr[288+256+a*16+b]);
            }
            s_u.kv[e][o] = val * nrm;
        }
        // rep 2: o = 32+j  (v0 for o<36, v1 for 36..47)
        {
            int o = 32 + j; float val;
            if (o < 36) {
                int b = o-20; val = 0.f;
                #pragma unroll
                for (int a = 0; a < A0c; a++) val += fs0[a]*bf2f(wr[288+a*16+b]);
                #pragma unroll
                for (int a = 0; a < A1c; a++) val += dt[a]*bf2f(wr[288+256+a*16+b]);
            } else {
                int idx = o-36, b = idx/3, i = idx%3;
                float t0 = 0.f, t1 = 0.f;
                #pragma unroll
                for (int a = 0; a < A0c; a++) t0 += fs0[a]*bf2f(wr[288+384+a*8+b]);
                #pragma unroll
                for (int a = 0; a < A1c; a++) t1 += fs1[a*3+i]*bf2f(wr[288+512+a*8+b]);
                val = t0*y1[i] + t1;
            }
            s_u.kv[e][o] = val * nrm;
        }
        // rep 3: o = 48+j (v1; j<12)
        if (j < 12) {
            int o = 48 + j;
            int idx = o-36, b = idx/3, i = idx%3;
            float t0 = 0.f, t1 = 0.f;
            #pragma unroll
            for (int a = 0; a < A0c; a++) t0 += fs0[a]*bf2f(wr[288+384+a*8+b]);
            #pragma unroll
            for (int a = 0; a < A1c; a++) t1 += fs1[a*3+i]*bf2f(wr[288+512+a*8+b]);
            s_u.kv[e][o] = (t0*y1[i] + t1) * nrm;
        }
    }
    __syncthreads();

    // ---- Phase EF: logits + softmax (wave 0, width-8 shuffles) ----
    if (tid < 64) {
        int e = tid & 15, n = e >> 3;
        float s0 = 0.f;
        #pragma unroll
        for (int a = 0; a < Q0c; a++) {
            float qa = s_q0[n][a];
            #pragma unroll
            for (int b = 0; b < Q0c; b++) s0 += qa * s_u.kv[e][b] * Wd0[a*8+b];
        }
        float s1 = 0.f;
        #pragma unroll
        for (int a = 0; a < Q1c; a++) {
            #pragma unroll
            for (int b = 0; b < Q1c; b++) {
                float d = s_q1[n][a*3+0]*s_u.kv[e][8+b*3+0]
                        + s_q1[n][a*3+1]*s_u.kv[e][8+b*3+1]
                        + s_q1[n][a*3+2]*s_u.kv[e][8+b*3+2];
                s1 += d * Wd1[a*4+b];
            }
        }
        float L = (s0 + s1*0.5773502691896258f) * 0.11180339887498948f;
        float m = L;
        m = fmaxf(m, __shfl_xor(m, 1, 8));
        m = fmaxf(m, __shfl_xor(m, 2, 8));
        m = fmaxf(m, __shfl_xor(m, 4, 8));
        float z = expf(L - m);
        float ssum = z;
        ssum += __shfl_xor(ssum, 1, 8);
        ssum += __shfl_xor(ssum, 2, 8);
        ssum += __shfl_xor(ssum, 4, 8);
        float alpha = z / ssum * s_cut[e];
        if (tid < 16) s_we[e] = sqrtf(alpha + 1e-12f);
    }
    __syncthreads();

    // ---- Phase G: weighted sum -> out ----
    if (tid < NPB*40) {
        int n = tid/40, c = tid%40;
        float acc = 0.f;
        #pragma unroll
        for (int e = 0; e < 8; e++) acc += s_we[n*8+e]*s_u.kv[n*8+e][20+c];
        out[(node0+n)*40 + c] = acc;
    }
}

extern "C" void kernel_launch(void* const* d_in, const int* in_sizes, int n_in,
                              void* d_out, int out_size, void* d_ws, size_t ws_size,
                              hipStream_t stream) {
    const float* f    = (const float*)d_in[0];
    const float* pos  = (const float*)d_in[1];
    const float* W1k  = (const float*)d_in[2];
    const float* W2k  = (const float*)d_in[3];
    const float* W1v  = (const float*)d_in[4];
    const float* W2v  = (const float*)d_in[5];
    const float* Wq0  = (const float*)d_in[6];
    const float* Wq1  = (const float*)d_in[7];
    const float* Wd0  = (const float*)d_in[8];
    const float* Wd1  = (const float*)d_in[9];
    const int*   esrc = (const int*)d_in[11];
    float* out = (float*)d_out;

    unsigned short* w2t_hi = (unsigned short*)d_ws;
    unsigned short* w2t_lo = w2t_hi + TOTC*HID;   // 55296 elems each

    hipLaunchKernelGGL(w2_prep, dim3(TOTC*HID/256), dim3(256), 0, stream,
                       W2k, W2v, w2t_hi, w2t_lo);
    hipLaunchKernelGGL(se3_fused, dim3(NN/NPB), dim3(256), 0, stream,
                       f, pos, W1k, W1v, Wq0, Wq1, Wd0, Wd1, esrc,
                       w2t_hi, w2t_lo, out);
}

// Round 15
// 203.762 us; speedup vs baseline: 3.0365x; 1.0599x over previous
//
#include <hip/hip_runtime.h>
#include <hip/hip_bf16.h>
#include <math.h>

// SE3Transformer fused kernel. R15: fast-math VALU diet (v_exp/v_rcp/v_rsq,
// compiler bf16 cvt), 0.125 folded into prep, coalesced w2_prep.
// Phase C: MFMA 16x16x32 bf16 split hi/lo (3-product), 4 blocks/CU.
#define NN    20000
#define NBF   16
#define HID   64
#define A0c   16
#define A1c   8
#define Q0c   8
#define Q1c   4
#define WKC   288
#define WVC   576
#define TOTC  864    // 54 MFMA N-tiles of 16
#define EPB   16
#define NPB   2
#define WP2   868    // bf16 wkv row pad

typedef __attribute__((ext_vector_type(8))) short bf16x8;
typedef __attribute__((ext_vector_type(4))) float f32x4;

static __device__ __forceinline__ unsigned short f2bf(float x) {
    __hip_bfloat16 h = __float2bfloat16(x);     // RNE; compiler may fuse cvt_pk
    return __hip_bfloat16_raw(h).x;
}
static __device__ __forceinline__ float bf2f(unsigned short h) {
    return __uint_as_float(((unsigned int)h) << 16);
}
static __device__ __forceinline__ float fast_rcp(float x) {
    return __builtin_amdgcn_rcpf(x);
}

// Prep (coalesced): one k-row (64 rows) per block; reads contiguous, writes
// tile-contiguous layout idx = ((t*2+ks)*64 + kq*16 + er)*8 + j with the
// 1/8 = W2/sqrt(64) scale folded in (exact: power of two).
__global__ __launch_bounds__(256) void w2_prep(const float* __restrict__ W2k,
                                               const float* __restrict__ W2v,
                                               unsigned short* __restrict__ hi,
                                               unsigned short* __restrict__ lo) {
    int k  = blockIdx.x;                        // 0..63
    int ks = k >> 5, kq = (k >> 3) & 3, j = k & 7;
    for (int r = 0; r < 4; r++) {
        int n = r*256 + threadIdx.x;
        if (n < TOTC) {
            float w = ((n < WKC) ? W2k[k*WKC + n] : W2v[k*WVC + (n - WKC)]) * 0.125f;
            unsigned short h = f2bf(w);
            int t = n >> 4, er = n & 15;
            int oidx = ((((t*2 + ks)*4 + kq)*16 + er) << 3) | j;
            hi[oidx] = h;
            lo[oidx] = f2bf(w - bf2f(h));
        }
    }
}

union HkKv {
    struct {
        unsigned short hk_hi[EPB][HID];
        unsigned short hk_lo[EPB][HID];
        unsigned short hv_hi[EPB][HID];
        unsigned short hv_lo[EPB][HID];
    } h;                                   // live: Phase B write -> Phase C reg load
    float kv[EPB][60];                     // live: Phase D write -> Phase G
};

#define MFMA3(AH, AL, B_HI, B_LO, ACC) \
    ACC = __builtin_amdgcn_mfma_f32_16x16x32_bf16(AH, B_HI, ACC, 0,0,0); \
    ACC = __builtin_amdgcn_mfma_f32_16x16x32_bf16(AL, B_HI, ACC, 0,0,0); \
    ACC = __builtin_amdgcn_mfma_f32_16x16x32_bf16(AH, B_LO, ACC, 0,0,0);

__global__ __launch_bounds__(256, 4)
void se3_fused(const float* __restrict__ f,
               const float* __restrict__ pos,
               const float* __restrict__ W1k,
               const float* __restrict__ W1v,
               const float* __restrict__ Wq0,
               const float* __restrict__ Wq1,
               const float* __restrict__ Wd0,
               const float* __restrict__ Wd1,
               const int* __restrict__ esrc,
               const unsigned short* __restrict__ w2t_hi,
               const unsigned short* __restrict__ w2t_lo,
               float* __restrict__ out)
{
    const int tid   = threadIdx.x;
    const int e0    = blockIdx.x * EPB;
    const int node0 = blockIdx.x * NPB;

    __shared__ float s_fs0[EPB][A0c];
    __shared__ float s_fs1[EPB][A1c*3];
    __shared__ float s_dot[EPB][A1c];
    __shared__ float s_y1[EPB][4];
    __shared__ float s_basis[EPB][NBF];
    __shared__ float s_cut[EPB];
    __shared__ __align__(16) HkKv s_u;
    __shared__ unsigned short s_wkv[EPB][WP2];   // bf16 wkv
    __shared__ float s_q0[NPB][Q0c];
    __shared__ float s_q1[NPB][Q1c*3];
    __shared__ float s_we[EPB];

    // ---- Phase A: geometry + basis + gathers + queries (one phase) ----
    {
        int e = tid >> 4, c = tid & 15;
        int src = esrc[e0 + e];
        int dst = node0 + (e >> 3);              // edge_dst = repeat(arange(N), K)
        float dx = pos[src*3+0] - pos[dst*3+0];
        float dy = pos[src*3+1] - pos[dst*3+1];
        float dz = pos[src*3+2] - pos[dst*3+2];
        float d2 = dx*dx + dy*dy + dz*dz + 1e-12f;
        float inv_r = __builtin_amdgcn_rsqf(d2);
        float r = d2 * inv_r;
        const float step = 3.5f / 17.0f;
        float ctr = step * (float)(c + 1);
        float tt  = (r - ctr) * (1.0f/step);
        s_basis[e][c] = __expf(-tt*tt) * (4.0f/1.12f);
        s_fs0[e][c]   = f[src*40 + c];
        s_fs1[e][c]   = f[src*40 + 16 + c];
        if (c < 8) s_fs1[e][16 + c] = f[src*40 + 32 + c];
        if (c == 0) {
            const float s3 = 1.7320508075688772f;
            s_y1[e][0] = s3*dx*inv_r;
            s_y1[e][1] = s3*dy*inv_r;
            s_y1[e][2] = s3*dz*inv_r;
            float xcut = 10.0f*(1.0f - r*(1.0f/3.5f));
            s_cut[e] = (xcut > 0.0f) ? __expf(-fast_rcp(xcut)) : 0.0f;
        }
        if (tid >= 240) {                        // q0 = f0 @ Wq0 / 4
            int idx = tid - 240, n = idx >> 3, q = idx & 7;
            const float* fn = f + (node0+n)*40;
            float acc = 0.f;
            #pragma unroll
            for (int a = 0; a < A0c; a++) acc += fn[a]*Wq0[a*Q0c+q];
            s_q0[n][q] = acc * 0.25f;
        }
        if (tid >= 192 && tid < 216) {           // q1 = einsum(f1,Wq1)/sqrt(8)
            int idx = tid - 192, n = idx/12, qi = idx%12, q = qi/3, i = qi%3;
            const float* fn = f + (node0+n)*40 + 16;
            float acc = 0.f;
            #pragma unroll
            for (int a = 0; a < A1c; a++) acc += fn[a*3+i]*Wq1[a*Q1c+q];
            s_q1[n][qi] = acc * 0.35355339059327373f;
        }
    }
    __syncthreads();

    // ---- Phase B: dot11 + hidden vectors hk/hv -> bf16 hi/lo, swizzled ----
    if (tid < EPB*A1c) {
        int e = tid >> 3, a = tid & 7;
        float acc = s_fs1[e][a*3+0]*s_y1[e][0]
                  + s_fs1[e][a*3+1]*s_y1[e][1]
                  + s_fs1[e][a*3+2]*s_y1[e][2];
        s_dot[e][a] = acc * 0.5773502691896258f;
    }
    {
        int wid = tid >> 6, lane = tid & 63;
        float w1k_r[NBF], w1v_r[NBF];            // hoisted: rep-invariant
        #pragma unroll
        for (int nb = 0; nb < NBF; nb++) {
            w1k_r[nb] = W1k[nb*HID + lane];
            w1v_r[nb] = W1v[nb*HID + lane];
        }
        for (int rep = 0; rep < 4; rep++) {
            int e = rep*4 + wid;
            float ak = 0.f, av = 0.f;
            #pragma unroll
            for (int nb = 0; nb < NBF; nb++) {
                float b = s_basis[e][nb];
                ak += b * w1k_r[nb];
                av += b * w1v_r[nb];
            }
            ak *= 0.25f; av *= 0.25f;
            ak = ak * fast_rcp(1.0f + __expf(-ak));   // silu, fast
            av = av * fast_rcp(1.0f + __expf(-av));
            int sw = (((lane>>3) ^ (e&7)) << 3) | (lane & 7);
            unsigned short khi = f2bf(ak);
            s_u.h.hk_hi[e][sw] = khi;
            s_u.h.hk_lo[e][sw] = f2bf(ak - bf2f(khi));
            unsigned short vhi = f2bf(av);
            s_u.h.hv_hi[e][sw] = vhi;
            s_u.h.hv_lo[e][sw] = f2bf(av - bf2f(vhi));
        }
    }
    __syncthreads();

    // ---- Phase C: wkv = h @ (W2/8) via MFMA, software-prefetched B tiles ----
    {
        int lane = tid & 63;
        int wid  = tid >> 6;
        int er   = lane & 15;
        int kq   = lane >> 4;
        bf16x8 ak_hi[2], ak_lo[2], av_hi[2], av_lo[2];
        #pragma unroll
        for (int ks = 0; ks < 2; ks++) {
            int csw = (((ks*4 + kq) ^ (er & 7)) << 3);
            ak_hi[ks] = *(const bf16x8*)&s_u.h.hk_hi[er][csw];
            ak_lo[ks] = *(const bf16x8*)&s_u.h.hk_lo[er][csw];
            av_hi[ks] = *(const bf16x8*)&s_u.h.hv_hi[er][csw];
            av_lo[ks] = *(const bf16x8*)&s_u.h.hv_lo[er][csw];
        }
        const unsigned short* bp_hi = w2t_hi + wid*1024 + lane*8;
        const unsigned short* bp_lo = w2t_lo + wid*1024 + lane*8;
        bf16x8 pb0 = *(const bf16x8*)(bp_hi);
        bf16x8 pb1 = *(const bf16x8*)(bp_hi + 512);
        bf16x8 pb2 = *(const bf16x8*)(bp_lo);
        bf16x8 pb3 = *(const bf16x8*)(bp_lo + 512);
        for (int t = wid; t < 54; t += 4) {
            bf16x8 cb0 = pb0, cb1 = pb1, cb2 = pb2, cb3 = pb3;
            if (t + 4 < 54) {                     // prefetch next tile
                bp_hi += 4096; bp_lo += 4096;
                pb0 = *(const bf16x8*)(bp_hi);
                pb1 = *(const bf16x8*)(bp_hi + 512);
                pb2 = *(const bf16x8*)(bp_lo);
                pb3 = *(const bf16x8*)(bp_lo + 512);
            }
            f32x4 acc = {0.f, 0.f, 0.f, 0.f};
            if (t < 18) {                         // k-path (wave-uniform branch)
                MFMA3(ak_hi[0], ak_lo[0], cb0, cb2, acc);
                MFMA3(ak_hi[1], ak_lo[1], cb1, cb3, acc);
            } else {                              // v-path
                MFMA3(av_hi[0], av_lo[0], cb0, cb2, acc);
                MFMA3(av_hi[1], av_lo[1], cb1, cb3, acc);
            }
            #pragma unroll
            for (int r = 0; r < 4; r++)
                s_wkv[kq*4 + r][t*16 + er] = f2bf(acc[r]);
        }
    }
    __syncthreads();

    // ---- Phase D: tensor product, thread (e, j) -> outputs j, j+16, j+32, j+48
    {
        const float nrm = 0.2041241452319315f;   // 1/sqrt(A0+A1)
        int e = tid >> 4, j = tid & 15;
        const unsigned short* wr = &s_wkv[e][0];
        const float* fs0 = &s_fs0[e][0];
        const float* fs1 = &s_fs1[e][0];
        const float* dt  = &s_dot[e][0];
        const float* y1  = &s_y1[e][0];
        // rep 0: o = j  (k0 for o<8, k1 for 8..15)
        {
            int o = j; float val;
            if (o < 8) {
                int b = o; val = 0.f;
                #pragma unroll
                for (int a = 0; a < A0c; a++) val += fs0[a]*bf2f(wr[a*8+b]);
                #pragma unroll
                for (int a = 0; a < A1c; a++) val += dt[a]*bf2f(wr[128+a*8+b]);
            } else {
                int idx = o-8, b = idx/3, i = idx%3;
                float t0 = 0.f, t1 = 0.f;
                #pragma unroll
                for (int a = 0; a < A0c; a++) t0 += fs0[a]*bf2f(wr[192+a*4+b]);
                #pragma unroll
                for (int a = 0; a < A1c; a++) t1 += fs1[a*3+i]*bf2f(wr[256+a*4+b]);
                val = t0*y1[i] + t1;
            }
            s_u.kv[e][o] = val * nrm;
        }
        // rep 1: o = 16+j  (k1 for o<20, v0 for 20..31)
        {
            int o = 16 + j; float val;
            if (o < 20) {
                int idx = o-8, b = idx/3, i = idx%3;
                float t0 = 0.f, t1 = 0.f;
                #pragma unroll
                for (int a = 0; a < A0c; a++) t0 += fs0[a]*bf2f(wr[192+a*4+b]);
                #pragma unroll
                for (int a = 0; a < A1c; a++) t1 += fs1[a*3+i]*bf2f(wr[256+a*4+b]);
                val = t0*y1[i] + t1;
            } else {
                int b = o-20; val = 0.f;
                #pragma unroll
                for (int a = 0; a < A0c; a++) val += fs0[a]*bf2f(wr[288+a*16+b]);
                #pragma unroll
                for (int a = 0; a < A1c; a++) val += dt[a]*bf2f(wr[288+256+a*16+b]);
            }
            s_u.kv[e][o] = val * nrm;
        }
        // rep 2: o = 32+j  (v0 for o<36, v1 for 36..47)
        {
            int o = 32 + j; float val;
            if (o < 36) {
                int b = o-20; val = 0.f;
                #pragma unroll
                for (int a = 0; a < A0c; a++) val += fs0[a]*bf2f(wr[288+a*16+b]);
                #pragma unroll
                for (int a = 0; a < A1c; a++) val += dt[a]*bf2f(wr[288+256+a*16+b]);
            } else {
                int idx = o-36, b = idx/3, i = idx%3;
                float t0 = 0.f, t1 = 0.f;
                #pragma unroll
                for (int a = 0; a < A0c; a++) t0 += fs0[a]*bf2f(wr[288+384+a*8+b]);
                #pragma unroll
                for (int a = 0; a < A1c; a++) t1 += fs1[a*3+i]*bf2f(wr[288+512+a*8+b]);
                val = t0*y1[i] + t1;
            }
            s_u.kv[e][o] = val * nrm;
        }
        // rep 3: o = 48+j (v1; j<12)
        if (j < 12) {
            int o = 48 + j;
            int idx = o-36, b = idx/3, i = idx%3;
            float t0 = 0.f, t1 = 0.f;
            #pragma unroll
            for (int a = 0; a < A0c; a++) t0 += fs0[a]*bf2f(wr[288+384+a*8+b]);
            #pragma unroll
            for (int a = 0; a < A1c; a++) t1 += fs1[a*3+i]*bf2f(wr[288+512+a*8+b]);
            s_u.kv[e][o] = (t0*y1[i] + t1) * nrm;
        }
    }
    __syncthreads();

    // ---- Phase EF: logits + softmax (wave 0, width-8 shuffles) ----
    if (tid < 64) {
        int e = tid & 15, n = e >> 3;
        float s0 = 0.f;
        #pragma unroll
        for (int a = 0; a < Q0c; a++) {
            float qa = s_q0[n][a];
            #pragma unroll
            for (int b = 0; b < Q0c; b++) s0 += qa * s_u.kv[e][b] * Wd0[a*8+b];
        }
        float s1 = 0.f;
        #pragma unroll
        for (int a = 0; a < Q1c; a++) {
            #pragma unroll
            for (int b = 0; b < Q1c; b++) {
                float d = s_q1[n][a*3+0]*s_u.kv[e][8+b*3+0]
                        + s_q1[n][a*3+1]*s_u.kv[e][8+b*3+1]
                        + s_q1[n][a*3+2]*s_u.kv[e][8+b*3+2];
                s1 += d * Wd1[a*4+b];
            }
        }
        float L = (s0 + s1*0.5773502691896258f) * 0.11180339887498948f;
        float m = L;
        m = fmaxf(m, __shfl_xor(m, 1, 8));
        m = fmaxf(m, __shfl_xor(m, 2, 8));
        m = fmaxf(m, __shfl_xor(m, 4, 8));
        float z = __expf(L - m);
        float ssum = z;
        ssum += __shfl_xor(ssum, 1, 8);
        ssum += __shfl_xor(ssum, 2, 8);
        ssum += __shfl_xor(ssum, 4, 8);
        float alpha = z * fast_rcp(ssum) * s_cut[e];
        if (tid < 16) s_we[e] = __builtin_amdgcn_sqrtf(alpha + 1e-12f);
    }
    __syncthreads();

    // ---- Phase G: weighted sum -> out ----
    if (tid < NPB*40) {
        int n = tid/40, c = tid%40;
        float acc = 0.f;
        #pragma unroll
        for (int e = 0; e < 8; e++) acc += s_we[n*8+e]*s_u.kv[n*8+e][20+c];
        out[(node0+n)*40 + c] = acc;
    }
}

extern "C" void kernel_launch(void* const* d_in, const int* in_sizes, int n_in,
                              void* d_out, int out_size, void* d_ws, size_t ws_size,
                              hipStream_t stream) {
    const float* f    = (const float*)d_in[0];
    const float* pos  = (const float*)d_in[1];
    const float* W1k  = (const float*)d_in[2];
    const float* W2k  = (const float*)d_in[3];
    const float* W1v  = (const float*)d_in[4];
    const float* W2v  = (const float*)d_in[5];
    const float* Wq0  = (const float*)d_in[6];
    const float* Wq1  = (const float*)d_in[7];
    const float* Wd0  = (const float*)d_in[8];
    const float* Wd1  = (const float*)d_in[9];
    const int*   esrc = (const int*)d_in[11];
    float* out = (float*)d_out;

    unsigned short* w2t_hi = (unsigned short*)d_ws;
    unsigned short* w2t_lo = w2t_hi + TOTC*HID;   // 55296 elems each

    hipLaunchKernelGGL(w2_prep, dim3(HID), dim3(256), 0, stream,
                       W2k, W2v, w2t_hi, w2t_lo);
    hipLaunchKernelGGL(se3_fused, dim3(NN/NPB), dim3(256), 0, stream,
                       f, pos, W1k, W1v, Wq0, Wq1, Wd0, Wd1, esrc,
                       w2t_hi, w2t_lo, out);
}